// Round 8
// baseline (939.777 us; speedup 1.0000x reference)
//
#include <hip/hip_runtime.h>

#define N_NODES 100000
#define N_EDGES 1600000
#define NB 391                 // buckets of 256 nodes: bucket = dst >> 8

typedef unsigned int uint32;

// bf16 round-to-nearest-even helpers
__device__ __forceinline__ uint32 bf16_rne(float f) {
    uint32 u = __float_as_uint(f);
    return (u + 0x7fffu + ((u >> 16) & 1u)) >> 16;
}
__device__ __forceinline__ uint32 pack_bf16x2(float lo, float hi) {
    return bf16_rne(lo) | (bf16_rne(hi) << 16);
}
__device__ __forceinline__ float bf16_lo(uint32 u) { return __uint_as_float(u << 16); }
__device__ __forceinline__ float bf16_hi(uint32 u) { return __uint_as_float(u & 0xFFFF0000u); }

// ===========================================================================
// x [N,128] f32 -> packed bf16 (one uint32 = 2 features)
// ===========================================================================
__global__ __launch_bounds__(256) void conv_x(const float* __restrict__ x,
                                              uint32* __restrict__ xb) {
    const int t = blockIdx.x * 256 + threadIdx.x;   // over N*64
    if (t >= N_NODES * 64) return;
    const float2 v = ((const float2*)x)[t];
    xb[t] = pack_bf16x2(v.x, v.y);
}

// ===========================================================================
// Bucketed CSR build. k1: bucket histogram (LDS-merged).
// ===========================================================================
__global__ __launch_bounds__(256) void bucket_hist(const int* __restrict__ dst,
                                                   int* __restrict__ bktCnt) {
    __shared__ int h[NB];
    for (int i = threadIdx.x; i < NB; i += 256) h[i] = 0;
    __syncthreads();
    for (int e = blockIdx.x * 256 + threadIdx.x; e < N_EDGES; e += NB * 256)
        atomicAdd(&h[dst[e] >> 8], 1);
    __syncthreads();
    for (int i = threadIdx.x; i < NB; i += 256)
        if (h[i]) atomicAdd(&bktCnt[i], h[i]);
}

// k2: exclusive scan of 391 bucket counts -> bases + cursors (single block).
__global__ __launch_bounds__(512) void bucket_scan(const int* __restrict__ bktCnt,
                                                   int* __restrict__ bBase,
                                                   int* __restrict__ bCur,
                                                   int* __restrict__ offs) {
    __shared__ int s[512];
    const int t = threadIdx.x;
    int v = (t < NB) ? bktCnt[t] : 0;
    s[t] = v;
    __syncthreads();
#pragma unroll
    for (int off = 1; off < 512; off <<= 1) {
        int u = (t >= off) ? s[t - off] : 0;
        __syncthreads();
        s[t] += u;
        __syncthreads();
    }
    if (t < NB) {
        const int excl = s[t] - v;
        bBase[t] = excl;
        bCur[t]  = excl;
    }
    if (t == 0) {
        bBase[NB] = N_EDGES;
        offs[N_NODES] = N_EDGES;
    }
}

// k3: scatter edges into per-bucket regions (append -> ~1x write amp).
// pack: bits 0..16 = src, bits 17..24 = dst & 255.
__global__ __launch_bounds__(256) void bucket_scatter(const int* __restrict__ dst,
                                                      const int* __restrict__ src,
                                                      const float* __restrict__ ew,
                                                      int* __restrict__ bCur,
                                                      int2* __restrict__ bucketed) {
    const int e = blockIdx.x * 256 + threadIdx.x;
    if (e >= N_EDGES) return;
    const int d = dst[e];
    const int p = atomicAdd(&bCur[d >> 8], 1);
    bucketed[p] = make_int2(src[e] | ((d & 255) << 17), __float_as_int(ew[e]));
}

// k4: one block per bucket: local 256-node histogram + scan in LDS, then
// place edges into the bucket's contiguous CSR window; emit offs.
__global__ __launch_bounds__(256) void bucket_csr(const int2* __restrict__ bucketed,
                                                  const int* __restrict__ bBase,
                                                  int* __restrict__ offs,
                                                  int2* __restrict__ csr_ef) {
    __shared__ int sdeg[256];
    __shared__ int lcur[256];
    const int b   = blockIdx.x;
    const int t   = threadIdx.x;
    const int beg = bBase[b], end = bBase[b + 1];

    sdeg[t] = 0;
    __syncthreads();
    for (int j = beg + t; j < end; j += 256)
        atomicAdd(&sdeg[(bucketed[j].x >> 17) & 255], 1);
    __syncthreads();
    const int mydeg = sdeg[t];
    // inclusive Hillis-Steele scan over 256
#pragma unroll
    for (int off = 1; off < 256; off <<= 1) {
        int u = (t >= off) ? sdeg[t - off] : 0;
        __syncthreads();
        sdeg[t] += u;
        __syncthreads();
    }
    const int excl = sdeg[t] - mydeg;
    lcur[t] = excl;
    const int node = b * 256 + t;
    if (node < N_NODES) offs[node] = beg + excl;
    __syncthreads();

    for (int j = beg + t; j < end; j += 256) {
        const int2 v = bucketed[j];
        const int dl = (v.x >> 17) & 255;
        const int p  = beg + atomicAdd(&lcur[dl], 1);
        csr_ef[p] = make_int2(v.x & 0x1FFFF, v.y);
    }
}

// ===========================================================================
// Gather-aggregate over bf16 feature tables, fp32 accumulate.
// ===========================================================================
template <int FEAT>
__global__ __launch_bounds__(256) void aggregate(const void* __restrict__ featv,
                                                 const int* __restrict__ offs,
                                                 const int2* __restrict__ csr_ef,
                                                 const float* __restrict__ bias,
                                                 float* __restrict__ out) {
    const int n    = (blockIdx.x * 256 + threadIdx.x) >> 6;
    const int lane = threadIdx.x & 63;
    if (n >= N_NODES) return;
    const int beg = offs[n], end = offs[n + 1];

    if constexpr (FEAT == 128) {
        const uint32* feat = (const uint32*)featv;
        float2 acc = make_float2(0.f, 0.f);
        int j = beg;
        for (; j + 3 < end; j += 4) {
            const int2 e0 = csr_ef[j],     e1 = csr_ef[j + 1];
            const int2 e2 = csr_ef[j + 2], e3 = csr_ef[j + 3];
            const uint32 v0 = feat[(size_t)e0.x * 64 + lane];
            const uint32 v1 = feat[(size_t)e1.x * 64 + lane];
            const uint32 v2 = feat[(size_t)e2.x * 64 + lane];
            const uint32 v3 = feat[(size_t)e3.x * 64 + lane];
            const float w0 = __int_as_float(e0.y), w1 = __int_as_float(e1.y);
            const float w2 = __int_as_float(e2.y), w3 = __int_as_float(e3.y);
            acc.x += w0 * bf16_lo(v0) + w1 * bf16_lo(v1) + w2 * bf16_lo(v2) + w3 * bf16_lo(v3);
            acc.y += w0 * bf16_hi(v0) + w1 * bf16_hi(v1) + w2 * bf16_hi(v2) + w3 * bf16_hi(v3);
        }
        for (; j < end; ++j) {
            const int2 e0 = csr_ef[j];
            const uint32 v = feat[(size_t)e0.x * 64 + lane];
            const float w = __int_as_float(e0.y);
            acc.x += w * bf16_lo(v);
            acc.y += w * bf16_hi(v);
        }
        ((float2*)(out + (size_t)n * 128))[lane] = acc;
    } else {
        const unsigned short* feat = (const unsigned short*)featv;
        float acc = bias[lane];
        int j = beg;
        for (; j + 3 < end; j += 4) {
            const int2 e0 = csr_ef[j],     e1 = csr_ef[j + 1];
            const int2 e2 = csr_ef[j + 2], e3 = csr_ef[j + 3];
            const float f0 = __uint_as_float((uint32)feat[(size_t)e0.x * 64 + lane] << 16);
            const float f1 = __uint_as_float((uint32)feat[(size_t)e1.x * 64 + lane] << 16);
            const float f2 = __uint_as_float((uint32)feat[(size_t)e2.x * 64 + lane] << 16);
            const float f3 = __uint_as_float((uint32)feat[(size_t)e3.x * 64 + lane] << 16);
            acc += __int_as_float(e0.y) * f0 + __int_as_float(e1.y) * f1
                 + __int_as_float(e2.y) * f2 + __int_as_float(e3.y) * f3;
        }
        for (; j < end; ++j) {
            const int2 e0 = csr_ef[j];
            acc += __int_as_float(e0.y)
                 * __uint_as_float((uint32)feat[(size_t)e0.x * 64 + lane] << 16);
        }
        out[(size_t)n * 64 + lane] = acc;
    }
}

// ===========================================================================
// Fused double GEMM, register-blocked, 512 threads (8 waves/CU), dynamic
// tile scheduling: sup2b[N,64](bf16) = relu(aggP[N,128] @ W1 + b1) @ W2
// Per thread phase A: 4 rows x 8 cols. LDS = 64+32+64 = exactly 160 KiB;
// the stolen tile index is broadcast through AT[0] (no extra LDS).
// ===========================================================================
__device__ __forceinline__ void fma4(float4& a, float s, const float4& v) {
    a.x += s * v.x; a.y += s * v.y; a.z += s * v.z; a.w += s * v.w;
}

__global__ __launch_bounds__(512) void gemm_fused(const float* __restrict__ aggP,
                                                  const float* __restrict__ W1,
                                                  const float* __restrict__ b1,
                                                  const float* __restrict__ W2,
                                                  uint32* __restrict__ sup2b,
                                                  int* __restrict__ tileCnt, int N) {
    __shared__ __align__(16) float W1s[128 * 128];  // 64 KB  [k][col]
    __shared__ __align__(16) float W2s[128 * 64];   // 32 KB  [k][col]
    __shared__ __align__(16) float AT[128 * 128];   // 64 KB  [k][row], reused as T^t
    float4* W14 = (float4*)W1s;
    float4* W24 = (float4*)W2s;
    float4* AT4 = (float4*)AT;

    for (int i = threadIdx.x; i < 128 * 32; i += 512) W14[i] = ((const float4*)W1)[i];
    for (int i = threadIdx.x; i < 128 * 16; i += 512) W24[i] = ((const float4*)W2)[i];

    const int rg = threadIdx.x & 31;   // rows rg*4 .. rg*4+3
    const int cg = threadIdx.x >> 5;   // cols cg*8 .. cg*8+7 (0..15)
    const float4 b1a = ((const float4*)b1)[cg * 2];
    const float4 b1b = ((const float4*)b1)[cg * 2 + 1];

    for (;;) {
        __syncthreads();  // prev phase-B reads of AT done (also covers W staging)
        if (threadIdx.x == 0) ((int*)AT)[0] = atomicAdd(tileCnt, 1);
        __syncthreads();
        const int tile = ((int*)AT)[0];
        __syncthreads();  // all threads read tile before stage-A overwrites AT[0]
        if (tile * 128 >= N) break;
        const int row0 = tile * 128;

        // ---- Stage A transposed: AT[k][row] --------------------------------
#pragma unroll
        for (int i = 0; i < 8; ++i) {
            const int idx  = i * 512 + threadIdx.x;
            const int row  = idx & 127;
            const int k4   = idx >> 7;          // 0..31
            const int grow = row0 + row;
            float4 v = make_float4(0.f, 0.f, 0.f, 0.f);
            if (grow < N) v = ((const float4*)aggP)[(size_t)grow * 32 + k4];
            AT[(k4 * 4 + 0) * 128 + row] = v.x;
            AT[(k4 * 4 + 1) * 128 + row] = v.y;
            AT[(k4 * 4 + 2) * 128 + row] = v.z;
            AT[(k4 * 4 + 3) * 128 + row] = v.w;
        }
        __syncthreads();

        // ---- Phase A: T = relu(A@W1 + b1), 4x8 per thread ------------------
        float4 acc[4][2];
#pragma unroll
        for (int i = 0; i < 4; ++i) {
            acc[i][0] = make_float4(0.f, 0.f, 0.f, 0.f);
            acc[i][1] = make_float4(0.f, 0.f, 0.f, 0.f);
        }
        float4 av = AT4[rg];
        float4 w0 = W14[cg * 2], w1 = W14[cg * 2 + 1];
        for (int k = 0; k < 128; ++k) {
            const int kn = (k + 1) & 127;
            const float4 nav = AT4[kn * 32 + rg];
            const float4 nw0 = W14[kn * 32 + cg * 2];
            const float4 nw1 = W14[kn * 32 + cg * 2 + 1];
            const float a[4] = {av.x, av.y, av.z, av.w};
#pragma unroll
            for (int i = 0; i < 4; ++i) {
                fma4(acc[i][0], a[i], w0);
                fma4(acc[i][1], a[i], w1);
            }
            av = nav; w0 = nw0; w1 = nw1;
        }
#pragma unroll
        for (int i = 0; i < 4; ++i) {
            acc[i][0].x = fmaxf(acc[i][0].x + b1a.x, 0.f);
            acc[i][0].y = fmaxf(acc[i][0].y + b1a.y, 0.f);
            acc[i][0].z = fmaxf(acc[i][0].z + b1a.z, 0.f);
            acc[i][0].w = fmaxf(acc[i][0].w + b1a.w, 0.f);
            acc[i][1].x = fmaxf(acc[i][1].x + b1b.x, 0.f);
            acc[i][1].y = fmaxf(acc[i][1].y + b1b.y, 0.f);
            acc[i][1].z = fmaxf(acc[i][1].z + b1b.z, 0.f);
            acc[i][1].w = fmaxf(acc[i][1].w + b1b.w, 0.f);
        }
        __syncthreads();  // all phase-A reads of AT done before overwrite

        // ---- Write T^t into AT: AT[c][r], c = cg*8+j, r = rg*4..+3 ---------
#pragma unroll
        for (int j = 0; j < 8; ++j) {
            const int jc = j & 3;
            const float* p0 = (const float*)&acc[0][j >> 2];
            const float* p1 = (const float*)&acc[1][j >> 2];
            const float* p2 = (const float*)&acc[2][j >> 2];
            const float* p3 = (const float*)&acc[3][j >> 2];
            AT4[(cg * 8 + j) * 32 + rg] = make_float4(p0[jc], p1[jc], p2[jc], p3[jc]);
        }
        __syncthreads();

        // ---- Phase B: out = T @ W2, 4 rows x 4 feats per thread, bf16 out --
        const int rg2 = threadIdx.x & 31;  // rows rg2*4..+3
        const int cg2 = threadIdx.x >> 5;  // 0..15 -> feats 4*cg2..+3
        float4 acc2[4];
#pragma unroll
        for (int i = 0; i < 4; ++i) acc2[i] = make_float4(0.f, 0.f, 0.f, 0.f);
        float4 tv4 = AT4[rg2];
        float4 wv = W24[cg2];
        for (int k = 0; k < 128; ++k) {
            const int kn = (k + 1) & 127;
            const float4 ntv = AT4[kn * 32 + rg2];
            const float4 nwv = W24[kn * 16 + cg2];
            const float tv[4] = {tv4.x, tv4.y, tv4.z, tv4.w};
#pragma unroll
            for (int i = 0; i < 4; ++i) { fma4(acc2[i], tv[i], wv); }
            tv4 = ntv; wv = nwv;
        }
#pragma unroll
        for (int i = 0; i < 4; ++i) {
            const int row = row0 + rg2 * 4 + i;
            if (row < N) {
                uint2 pk;
                pk.x = pack_bf16x2(acc2[i].x, acc2[i].y);
                pk.y = pack_bf16x2(acc2[i].z, acc2[i].w);
                ((uint2*)sup2b)[(size_t)row * 16 + cg2] = pk;
            }
        }
    }
}

extern "C" void kernel_launch(void* const* d_in, const int* in_sizes, int n_in,
                              void* d_out, int out_size, void* d_ws, size_t ws_size,
                              hipStream_t stream) {
    const float* x  = (const float*)d_in[0];
    const int*   ei = (const int*)d_in[1];   // [2, E]: row 0 = dst, row 1 = src
    const float* ew = (const float*)d_in[2];
    const float* W1 = (const float*)d_in[3];
    const float* b1 = (const float*)d_in[4];
    const float* W2 = (const float*)d_in[5];
    const float* b2 = (const float*)d_in[6];
    float* out = (float*)d_out;

    const int* dstIdx = ei;
    const int* srcIdx = ei + N_EDGES;

    // Workspace (~90 MB):
    //   xb [N*64 uint, 25.6 MB]  -> aliased by sup2b after aggregate<128>
    //   aggP [N*128 f32, 51.2 MB] -> aliased by `bucketed` during CSR build
    //   csr_ef [E int2, 12.8 MB], small arrays after.
    uint32* xb      = (uint32*)d_ws;
    float*  aggP    = (float*)(xb + (size_t)N_NODES * 64);
    int2*   csr_ef  = (int2*)(aggP + (size_t)N_NODES * 128);
    int*    bktCnt  = (int*)(csr_ef + N_EDGES);   // NB
    int*    tileCnt = bktCnt + NB;                // 1 (memset together with bktCnt)
    int*    bBase   = tileCnt + 1;                // NB+1
    int*    bCur    = bBase + NB + 1;             // NB
    int*    offs    = bCur + NB;                  // N+1
    int2*   bucketed = (int2*)aggP;               // alias (dead before aggP written)
    uint32* sup2b   = xb;                         // alias (dead before sup2b written)

    const int eblocks = (N_EDGES + 255) / 256;

    // --- zero bucket counts + tile counter (one memset) ---
    (void)hipMemsetAsync(bktCnt, 0, (NB + 1) * sizeof(int), stream);
    conv_x<<<(N_NODES * 64 + 255) / 256, 256, 0, stream>>>(x, xb);

    // --- bucketed CSR build ---
    bucket_hist<<<NB, 256, 0, stream>>>(dstIdx, bktCnt);
    bucket_scan<<<1, 512, 0, stream>>>(bktCnt, bBase, bCur, offs);
    bucket_scatter<<<eblocks, 256, 0, stream>>>(dstIdx, srcIdx, ew, bCur, bucketed);
    bucket_csr<<<NB, 256, 0, stream>>>(bucketed, bBase, offs, csr_ef);

    // --- Layer 1 aggregate-first: aggP = A @ x  (bf16 gather, fp32 acc) ---
    aggregate<128><<<(N_NODES * 64) / 256, 256, 0, stream>>>(xb, offs, csr_ef,
                                                             nullptr, aggP);
    // --- Fused transform: sup2b = bf16(relu(aggP@W1 + b1) @ W2) ---
    gemm_fused<<<256, 512, 0, stream>>>(aggP, W1, b1, W2, sup2b, tileCnt, N_NODES);

    // --- Layer 2 aggregate (bf16 gather), bias b2 folded in ---
    aggregate<64><<<(N_NODES * 64) / 256, 256, 0, stream>>>(sup2b, offs, csr_ef,
                                                            b2, out);
}

// Round 9
// 437.018 us; speedup vs baseline: 2.1504x; 2.1504x over previous
//
#include <hip/hip_runtime.h>

#define N_NODES 100000
#define N_EDGES 1600000
#define NB 391                 // buckets of 256 nodes: bucket = dst >> 8
#define PAD 16                 // pad atomic counters to one 64B line each
#define SC_EPB 2048            // edges per scatter block
#define SC_BLOCKS ((N_EDGES + SC_EPB - 1) / SC_EPB)   // 782

typedef unsigned int uint32;

// bf16 round-to-nearest-even helpers
__device__ __forceinline__ uint32 bf16_rne(float f) {
    uint32 u = __float_as_uint(f);
    return (u + 0x7fffu + ((u >> 16) & 1u)) >> 16;
}
__device__ __forceinline__ uint32 pack_bf16x2(float lo, float hi) {
    return bf16_rne(lo) | (bf16_rne(hi) << 16);
}
__device__ __forceinline__ float bf16_lo(uint32 u) { return __uint_as_float(u << 16); }
__device__ __forceinline__ float bf16_hi(uint32 u) { return __uint_as_float(u & 0xFFFF0000u); }

// ===========================================================================
// x [N,128] f32 -> packed bf16 (one uint32 = 2 features)
// ===========================================================================
__global__ __launch_bounds__(256) void conv_x(const float* __restrict__ x,
                                              uint32* __restrict__ xb) {
    const int t = blockIdx.x * 256 + threadIdx.x;   // over N*64
    if (t >= N_NODES * 64) return;
    const float2 v = ((const float2*)x)[t];
    xb[t] = pack_bf16x2(v.x, v.y);
}

// ===========================================================================
// k1: bucket histogram. LDS-merged; global counters PADDED (1 per 64B line).
// ===========================================================================
__global__ __launch_bounds__(256) void bucket_hist(const int* __restrict__ dst,
                                                   int* __restrict__ bktCnt) {
    __shared__ int h[NB];
    for (int i = threadIdx.x; i < NB; i += 256) h[i] = 0;
    __syncthreads();
    for (int e = blockIdx.x * 256 + threadIdx.x; e < N_EDGES; e += NB * 256)
        atomicAdd(&h[dst[e] >> 8], 1);
    __syncthreads();
    for (int i = threadIdx.x; i < NB; i += 256)
        if (h[i]) atomicAdd(&bktCnt[i * PAD], h[i]);
}

// k2: exclusive scan of 391 bucket counts -> bases + padded cursors.
__global__ __launch_bounds__(512) void bucket_scan(const int* __restrict__ bktCnt,
                                                   int* __restrict__ bBase,
                                                   int* __restrict__ bCur,
                                                   int* __restrict__ offs) {
    __shared__ int s[512];
    const int t = threadIdx.x;
    int v = (t < NB) ? bktCnt[t * PAD] : 0;
    s[t] = v;
    __syncthreads();
#pragma unroll
    for (int off = 1; off < 512; off <<= 1) {
        int u = (t >= off) ? s[t - off] : 0;
        __syncthreads();
        s[t] += u;
        __syncthreads();
    }
    if (t < NB) {
        const int excl = s[t] - v;
        bBase[t] = excl;
        bCur[t * PAD] = excl;
    }
    if (t == 0) {
        bBase[NB] = N_EDGES;
        offs[N_NODES] = N_EDGES;
    }
}

// k3: scatter edges into per-bucket regions. Hierarchical: per-block LDS
// histogram -> one bulk range-reservation atomic per (block,bucket) -> place
// via LDS cursors. Kills the 1.6M-atomics-on-25-lines serialization.
// pack: bits 0..16 = src, bits 17..24 = dst & 255.
__global__ __launch_bounds__(256) void bucket_scatter2(const int* __restrict__ dst,
                                                       const int* __restrict__ src,
                                                       const float* __restrict__ ew,
                                                       int* __restrict__ bCur,
                                                       int2* __restrict__ bucketed) {
    __shared__ int h[NB];
    __shared__ int cur[NB];
    const int base = blockIdx.x * SC_EPB;
    const int end  = min(base + SC_EPB, N_EDGES);

    for (int i = threadIdx.x; i < NB; i += 256) h[i] = 0;
    __syncthreads();
    for (int e = base + threadIdx.x; e < end; e += 256)
        atomicAdd(&h[dst[e] >> 8], 1);
    __syncthreads();
    for (int i = threadIdx.x; i < NB; i += 256) {
        const int c = h[i];
        cur[i] = c ? atomicAdd(&bCur[i * PAD], c) : 0;
    }
    __syncthreads();
    for (int e = base + threadIdx.x; e < end; e += 256) {
        const int d = dst[e];
        const int p = atomicAdd(&cur[d >> 8], 1);   // LDS atomic
        bucketed[p] = make_int2(src[e] | ((d & 255) << 17), __float_as_int(ew[e]));
    }
}

// k4: one block per bucket: local 256-node histogram + scan in LDS, then
// place edges into the bucket's contiguous CSR window; emit offs.
__global__ __launch_bounds__(256) void bucket_csr(const int2* __restrict__ bucketed,
                                                  const int* __restrict__ bBase,
                                                  int* __restrict__ offs,
                                                  int2* __restrict__ csr_ef) {
    __shared__ int sdeg[256];
    __shared__ int lcur[256];
    const int b   = blockIdx.x;
    const int t   = threadIdx.x;
    const int beg = bBase[b], end = bBase[b + 1];

    sdeg[t] = 0;
    __syncthreads();
    for (int j = beg + t; j < end; j += 256)
        atomicAdd(&sdeg[(bucketed[j].x >> 17) & 255], 1);
    __syncthreads();
    const int mydeg = sdeg[t];
#pragma unroll
    for (int off = 1; off < 256; off <<= 1) {
        int u = (t >= off) ? sdeg[t - off] : 0;
        __syncthreads();
        sdeg[t] += u;
        __syncthreads();
    }
    const int excl = sdeg[t] - mydeg;
    lcur[t] = excl;
    const int node = b * 256 + t;
    if (node < N_NODES) offs[node] = beg + excl;
    __syncthreads();

    for (int j = beg + t; j < end; j += 256) {
        const int2 v = bucketed[j];
        const int dl = (v.x >> 17) & 255;
        const int p  = beg + atomicAdd(&lcur[dl], 1);
        csr_ef[p] = make_int2(v.x & 0x1FFFF, v.y);
    }
}

// ===========================================================================
// Gather-aggregate over bf16 feature tables, fp32 accumulate.
// ===========================================================================
template <int FEAT>
__global__ __launch_bounds__(256) void aggregate(const void* __restrict__ featv,
                                                 const int* __restrict__ offs,
                                                 const int2* __restrict__ csr_ef,
                                                 const float* __restrict__ bias,
                                                 float* __restrict__ out) {
    const int n    = (blockIdx.x * 256 + threadIdx.x) >> 6;
    const int lane = threadIdx.x & 63;
    if (n >= N_NODES) return;
    const int beg = offs[n], end = offs[n + 1];

    if constexpr (FEAT == 128) {
        const uint32* feat = (const uint32*)featv;
        float2 acc = make_float2(0.f, 0.f);
        int j = beg;
        for (; j + 3 < end; j += 4) {
            const int2 e0 = csr_ef[j],     e1 = csr_ef[j + 1];
            const int2 e2 = csr_ef[j + 2], e3 = csr_ef[j + 3];
            const uint32 v0 = feat[(size_t)e0.x * 64 + lane];
            const uint32 v1 = feat[(size_t)e1.x * 64 + lane];
            const uint32 v2 = feat[(size_t)e2.x * 64 + lane];
            const uint32 v3 = feat[(size_t)e3.x * 64 + lane];
            const float w0 = __int_as_float(e0.y), w1 = __int_as_float(e1.y);
            const float w2 = __int_as_float(e2.y), w3 = __int_as_float(e3.y);
            acc.x += w0 * bf16_lo(v0) + w1 * bf16_lo(v1) + w2 * bf16_lo(v2) + w3 * bf16_lo(v3);
            acc.y += w0 * bf16_hi(v0) + w1 * bf16_hi(v1) + w2 * bf16_hi(v2) + w3 * bf16_hi(v3);
        }
        for (; j < end; ++j) {
            const int2 e0 = csr_ef[j];
            const uint32 v = feat[(size_t)e0.x * 64 + lane];
            const float w = __int_as_float(e0.y);
            acc.x += w * bf16_lo(v);
            acc.y += w * bf16_hi(v);
        }
        ((float2*)(out + (size_t)n * 128))[lane] = acc;
    } else {
        const unsigned short* feat = (const unsigned short*)featv;
        float acc = bias[lane];
        int j = beg;
        for (; j + 3 < end; j += 4) {
            const int2 e0 = csr_ef[j],     e1 = csr_ef[j + 1];
            const int2 e2 = csr_ef[j + 2], e3 = csr_ef[j + 3];
            const float f0 = __uint_as_float((uint32)feat[(size_t)e0.x * 64 + lane] << 16);
            const float f1 = __uint_as_float((uint32)feat[(size_t)e1.x * 64 + lane] << 16);
            const float f2 = __uint_as_float((uint32)feat[(size_t)e2.x * 64 + lane] << 16);
            const float f3 = __uint_as_float((uint32)feat[(size_t)e3.x * 64 + lane] << 16);
            acc += __int_as_float(e0.y) * f0 + __int_as_float(e1.y) * f1
                 + __int_as_float(e2.y) * f2 + __int_as_float(e3.y) * f3;
        }
        for (; j < end; ++j) {
            const int2 e0 = csr_ef[j];
            acc += __int_as_float(e0.y)
                 * __uint_as_float((uint32)feat[(size_t)e0.x * 64 + lane] << 16);
        }
        out[(size_t)n * 64 + lane] = acc;
    }
}

// ===========================================================================
// Fused double GEMM, register-blocked, 512 threads, dynamic tile scheduling:
// sup2b[N,64](bf16) = relu(aggP[N,128] @ W1 + b1) @ W2.  LDS = 160 KiB exact;
// stolen tile index broadcast through AT[0].
// ===========================================================================
__device__ __forceinline__ void fma4(float4& a, float s, const float4& v) {
    a.x += s * v.x; a.y += s * v.y; a.z += s * v.z; a.w += s * v.w;
}

__global__ __launch_bounds__(512) void gemm_fused(const float* __restrict__ aggP,
                                                  const float* __restrict__ W1,
                                                  const float* __restrict__ b1,
                                                  const float* __restrict__ W2,
                                                  uint32* __restrict__ sup2b,
                                                  int* __restrict__ tileCnt, int N) {
    __shared__ __align__(16) float W1s[128 * 128];  // 64 KB  [k][col]
    __shared__ __align__(16) float W2s[128 * 64];   // 32 KB  [k][col]
    __shared__ __align__(16) float AT[128 * 128];   // 64 KB  [k][row], reused as T^t
    float4* W14 = (float4*)W1s;
    float4* W24 = (float4*)W2s;
    float4* AT4 = (float4*)AT;

    for (int i = threadIdx.x; i < 128 * 32; i += 512) W14[i] = ((const float4*)W1)[i];
    for (int i = threadIdx.x; i < 128 * 16; i += 512) W24[i] = ((const float4*)W2)[i];

    const int rg = threadIdx.x & 31;   // rows rg*4 .. rg*4+3
    const int cg = threadIdx.x >> 5;   // cols cg*8 .. cg*8+7 (0..15)
    const float4 b1a = ((const float4*)b1)[cg * 2];
    const float4 b1b = ((const float4*)b1)[cg * 2 + 1];

    for (;;) {
        __syncthreads();  // prev phase-B reads of AT done (also covers W staging)
        if (threadIdx.x == 0) ((int*)AT)[0] = atomicAdd(tileCnt, 1);
        __syncthreads();
        const int tile = ((int*)AT)[0];
        __syncthreads();  // all threads read tile before stage-A overwrites AT[0]
        if (tile * 128 >= N) break;
        const int row0 = tile * 128;

        // ---- Stage A transposed: AT[k][row] --------------------------------
#pragma unroll
        for (int i = 0; i < 8; ++i) {
            const int idx  = i * 512 + threadIdx.x;
            const int row  = idx & 127;
            const int k4   = idx >> 7;          // 0..31
            const int grow = row0 + row;
            float4 v = make_float4(0.f, 0.f, 0.f, 0.f);
            if (grow < N) v = ((const float4*)aggP)[(size_t)grow * 32 + k4];
            AT[(k4 * 4 + 0) * 128 + row] = v.x;
            AT[(k4 * 4 + 1) * 128 + row] = v.y;
            AT[(k4 * 4 + 2) * 128 + row] = v.z;
            AT[(k4 * 4 + 3) * 128 + row] = v.w;
        }
        __syncthreads();

        // ---- Phase A: T = relu(A@W1 + b1), 4x8 per thread ------------------
        float4 acc[4][2];
#pragma unroll
        for (int i = 0; i < 4; ++i) {
            acc[i][0] = make_float4(0.f, 0.f, 0.f, 0.f);
            acc[i][1] = make_float4(0.f, 0.f, 0.f, 0.f);
        }
        float4 av = AT4[rg];
        float4 w0 = W14[cg * 2], w1 = W14[cg * 2 + 1];
        for (int k = 0; k < 128; ++k) {
            const int kn = (k + 1) & 127;
            const float4 nav = AT4[kn * 32 + rg];
            const float4 nw0 = W14[kn * 32 + cg * 2];
            const float4 nw1 = W14[kn * 32 + cg * 2 + 1];
            const float a[4] = {av.x, av.y, av.z, av.w};
#pragma unroll
            for (int i = 0; i < 4; ++i) {
                fma4(acc[i][0], a[i], w0);
                fma4(acc[i][1], a[i], w1);
            }
            av = nav; w0 = nw0; w1 = nw1;
        }
#pragma unroll
        for (int i = 0; i < 4; ++i) {
            acc[i][0].x = fmaxf(acc[i][0].x + b1a.x, 0.f);
            acc[i][0].y = fmaxf(acc[i][0].y + b1a.y, 0.f);
            acc[i][0].z = fmaxf(acc[i][0].z + b1a.z, 0.f);
            acc[i][0].w = fmaxf(acc[i][0].w + b1a.w, 0.f);
            acc[i][1].x = fmaxf(acc[i][1].x + b1b.x, 0.f);
            acc[i][1].y = fmaxf(acc[i][1].y + b1b.y, 0.f);
            acc[i][1].z = fmaxf(acc[i][1].z + b1b.z, 0.f);
            acc[i][1].w = fmaxf(acc[i][1].w + b1b.w, 0.f);
        }
        __syncthreads();  // all phase-A reads of AT done before overwrite

        // ---- Write T^t into AT: AT[c][r], c = cg*8+j, r = rg*4..+3 ---------
#pragma unroll
        for (int j = 0; j < 8; ++j) {
            const int jc = j & 3;
            const float* p0 = (const float*)&acc[0][j >> 2];
            const float* p1 = (const float*)&acc[1][j >> 2];
            const float* p2 = (const float*)&acc[2][j >> 2];
            const float* p3 = (const float*)&acc[3][j >> 2];
            AT4[(cg * 8 + j) * 32 + rg] = make_float4(p0[jc], p1[jc], p2[jc], p3[jc]);
        }
        __syncthreads();

        // ---- Phase B: out = T @ W2, 4 rows x 4 feats per thread, bf16 out --
        const int rg2 = threadIdx.x & 31;  // rows rg2*4..+3
        const int cg2 = threadIdx.x >> 5;  // 0..15 -> feats 4*cg2..+3
        float4 acc2[4];
#pragma unroll
        for (int i = 0; i < 4; ++i) acc2[i] = make_float4(0.f, 0.f, 0.f, 0.f);
        float4 tv4 = AT4[rg2];
        float4 wv = W24[cg2];
        for (int k = 0; k < 128; ++k) {
            const int kn = (k + 1) & 127;
            const float4 ntv = AT4[kn * 32 + rg2];
            const float4 nwv = W24[kn * 16 + cg2];
            const float tv[4] = {tv4.x, tv4.y, tv4.z, tv4.w};
#pragma unroll
            for (int i = 0; i < 4; ++i) { fma4(acc2[i], tv[i], wv); }
            tv4 = ntv; wv = nwv;
        }
#pragma unroll
        for (int i = 0; i < 4; ++i) {
            const int row = row0 + rg2 * 4 + i;
            if (row < N) {
                uint2 pk;
                pk.x = pack_bf16x2(acc2[i].x, acc2[i].y);
                pk.y = pack_bf16x2(acc2[i].z, acc2[i].w);
                ((uint2*)sup2b)[(size_t)row * 16 + cg2] = pk;
            }
        }
    }
}

extern "C" void kernel_launch(void* const* d_in, const int* in_sizes, int n_in,
                              void* d_out, int out_size, void* d_ws, size_t ws_size,
                              hipStream_t stream) {
    const float* x  = (const float*)d_in[0];
    const int*   ei = (const int*)d_in[1];   // [2, E]: row 0 = dst, row 1 = src
    const float* ew = (const float*)d_in[2];
    const float* W1 = (const float*)d_in[3];
    const float* b1 = (const float*)d_in[4];
    const float* W2 = (const float*)d_in[5];
    const float* b2 = (const float*)d_in[6];
    float* out = (float*)d_out;

    const int* dstIdx = ei;
    const int* srcIdx = ei + N_EDGES;

    // Workspace (~90 MB):
    //   xb [N*64 uint, 25.6 MB]  -> aliased by sup2b after aggregate<128>
    //   aggP [N*128 f32, 51.2 MB] -> aliased by `bucketed` during CSR build
    //   csr_ef [E int2, 12.8 MB]; padded counters after (1 int per 64B line).
    uint32* xb      = (uint32*)d_ws;
    float*  aggP    = (float*)(xb + (size_t)N_NODES * 64);
    int2*   csr_ef  = (int2*)(aggP + (size_t)N_NODES * 128);
    int*    bktCnt  = (int*)(csr_ef + N_EDGES);   // NB*PAD (padded)
    int*    tileCnt = bktCnt + NB * PAD;          // 1 (memset together with bktCnt)
    int*    bCur    = tileCnt + 1;                // NB*PAD (padded; init by bucket_scan)
    int*    bBase   = bCur + NB * PAD;            // NB+1
    int*    offs    = bBase + NB + 1;             // N+1
    int2*   bucketed = (int2*)aggP;               // alias (dead before aggP written)
    uint32* sup2b   = xb;                         // alias (dead before sup2b written)

    // --- zero padded bucket counts + tile counter (one memset) ---
    (void)hipMemsetAsync(bktCnt, 0, (NB * PAD + 1) * sizeof(int), stream);
    conv_x<<<(N_NODES * 64 + 255) / 256, 256, 0, stream>>>(x, xb);

    // --- bucketed CSR build (padded counters, hierarchical reservation) ---
    bucket_hist<<<NB, 256, 0, stream>>>(dstIdx, bktCnt);
    bucket_scan<<<1, 512, 0, stream>>>(bktCnt, bBase, bCur, offs);
    bucket_scatter2<<<SC_BLOCKS, 256, 0, stream>>>(dstIdx, srcIdx, ew, bCur, bucketed);
    bucket_csr<<<NB, 256, 0, stream>>>(bucketed, bBase, offs, csr_ef);

    // --- Layer 1 aggregate-first: aggP = A @ x  (bf16 gather, fp32 acc) ---
    aggregate<128><<<(N_NODES * 64) / 256, 256, 0, stream>>>(xb, offs, csr_ef,
                                                             nullptr, aggP);
    // --- Fused transform: sup2b = bf16(relu(aggP@W1 + b1) @ W2) ---
    gemm_fused<<<256, 512, 0, stream>>>(aggP, W1, b1, W2, sup2b, tileCnt, N_NODES);

    // --- Layer 2 aggregate (bf16 gather), bias b2 folded in ---
    aggregate<64><<<(N_NODES * 64) / 256, 256, 0, stream>>>(sup2b, offs, csr_ef,
                                                            b2, out);
}

// Round 11
// 365.848 us; speedup vs baseline: 2.5688x; 1.1945x over previous
//
#include <hip/hip_runtime.h>

#define N_NODES 100000
#define N_EDGES 1600000
#define NB 391                 // buckets of 256 nodes: bucket = dst >> 8
#define PAD 16                 // pad atomic counters to one 64B line each
#define SC_EPB 2048            // edges per scatter block
#define SC_BLOCKS ((N_EDGES + SC_EPB - 1) / SC_EPB)   // 782
#define LDA 136                // LDS row stride in bf16 (128 + 8 pad)
#define NTILES ((N_NODES + 127) / 128)                // 782

typedef unsigned int uint32;
typedef __attribute__((ext_vector_type(8))) short bf16x8;
typedef __attribute__((ext_vector_type(4))) float f32x4;

// bf16 round-to-nearest-even helpers
__device__ __forceinline__ uint32 bf16_rne(float f) {
    uint32 u = __float_as_uint(f);
    return (u + 0x7fffu + ((u >> 16) & 1u)) >> 16;
}
__device__ __forceinline__ uint32 pack_bf16x2(float lo, float hi) {
    return bf16_rne(lo) | (bf16_rne(hi) << 16);
}
__device__ __forceinline__ float bf16_lo(uint32 u) { return __uint_as_float(u << 16); }
__device__ __forceinline__ float bf16_hi(uint32 u) { return __uint_as_float(u & 0xFFFF0000u); }

// ===========================================================================
// x [N,128] f32 -> packed bf16 (one uint32 = 2 features)
// ===========================================================================
__global__ __launch_bounds__(256) void conv_x(const float* __restrict__ x,
                                              uint32* __restrict__ xb) {
    const int t = blockIdx.x * 256 + threadIdx.x;   // over N*64
    if (t >= N_NODES * 64) return;
    const float2 v = ((const float2*)x)[t];
    xb[t] = pack_bf16x2(v.x, v.y);
}

// W1 [128,128] -> W1T bf16 [n=128][k=128]; W2 [128,64] -> W2T bf16 [n=64][k=128]
__global__ __launch_bounds__(256) void conv_w(const float* __restrict__ W1,
                                              const float* __restrict__ W2,
                                              uint32* __restrict__ w1tb,
                                              uint32* __restrict__ w2tb) {
    const int t = blockIdx.x * 256 + threadIdx.x;
    if (t < 128 * 64) {
        const int n = t >> 6, kk = t & 63;
        w1tb[t] = pack_bf16x2(W1[(2 * kk) * 128 + n], W1[(2 * kk + 1) * 128 + n]);
    } else if (t < 128 * 64 + 64 * 64) {
        const int u = t - 128 * 64;
        const int n = u >> 6, kk = u & 63;
        w2tb[u] = pack_bf16x2(W2[(2 * kk) * 64 + n], W2[(2 * kk + 1) * 64 + n]);
    }
}

// ===========================================================================
// Bucketed CSR build (unchanged from round 9).
// ===========================================================================
__global__ __launch_bounds__(256) void bucket_hist(const int* __restrict__ dst,
                                                   int* __restrict__ bktCnt) {
    __shared__ int h[NB];
    for (int i = threadIdx.x; i < NB; i += 256) h[i] = 0;
    __syncthreads();
    for (int e = blockIdx.x * 256 + threadIdx.x; e < N_EDGES; e += NB * 256)
        atomicAdd(&h[dst[e] >> 8], 1);
    __syncthreads();
    for (int i = threadIdx.x; i < NB; i += 256)
        if (h[i]) atomicAdd(&bktCnt[i * PAD], h[i]);
}

__global__ __launch_bounds__(512) void bucket_scan(const int* __restrict__ bktCnt,
                                                   int* __restrict__ bBase,
                                                   int* __restrict__ bCur,
                                                   int* __restrict__ offs) {
    __shared__ int s[512];
    const int t = threadIdx.x;
    int v = (t < NB) ? bktCnt[t * PAD] : 0;
    s[t] = v;
    __syncthreads();
#pragma unroll
    for (int off = 1; off < 512; off <<= 1) {
        int u = (t >= off) ? s[t - off] : 0;
        __syncthreads();
        s[t] += u;
        __syncthreads();
    }
    if (t < NB) {
        const int excl = s[t] - v;
        bBase[t] = excl;
        bCur[t * PAD] = excl;
    }
    if (t == 0) {
        bBase[NB] = N_EDGES;
        offs[N_NODES] = N_EDGES;
    }
}

__global__ __launch_bounds__(256) void bucket_scatter2(const int* __restrict__ dst,
                                                       const int* __restrict__ src,
                                                       const float* __restrict__ ew,
                                                       int* __restrict__ bCur,
                                                       int2* __restrict__ bucketed) {
    __shared__ int h[NB];
    __shared__ int cur[NB];
    const int base = blockIdx.x * SC_EPB;
    const int end  = min(base + SC_EPB, N_EDGES);

    for (int i = threadIdx.x; i < NB; i += 256) h[i] = 0;
    __syncthreads();
    for (int e = base + threadIdx.x; e < end; e += 256)
        atomicAdd(&h[dst[e] >> 8], 1);
    __syncthreads();
    for (int i = threadIdx.x; i < NB; i += 256) {
        const int c = h[i];
        cur[i] = c ? atomicAdd(&bCur[i * PAD], c) : 0;
    }
    __syncthreads();
    for (int e = base + threadIdx.x; e < end; e += 256) {
        const int d = dst[e];
        const int p = atomicAdd(&cur[d >> 8], 1);   // LDS atomic
        bucketed[p] = make_int2(src[e] | ((d & 255) << 17), __float_as_int(ew[e]));
    }
}

__global__ __launch_bounds__(256) void bucket_csr(const int2* __restrict__ bucketed,
                                                  const int* __restrict__ bBase,
                                                  int* __restrict__ offs,
                                                  int2* __restrict__ csr_ef) {
    __shared__ int sdeg[256];
    __shared__ int lcur[256];
    const int b   = blockIdx.x;
    const int t   = threadIdx.x;
    const int beg = bBase[b], end = bBase[b + 1];

    sdeg[t] = 0;
    __syncthreads();
    for (int j = beg + t; j < end; j += 256)
        atomicAdd(&sdeg[(bucketed[j].x >> 17) & 255], 1);
    __syncthreads();
    const int mydeg = sdeg[t];
#pragma unroll
    for (int off = 1; off < 256; off <<= 1) {
        int u = (t >= off) ? sdeg[t - off] : 0;
        __syncthreads();
        sdeg[t] += u;
        __syncthreads();
    }
    const int excl = sdeg[t] - mydeg;
    lcur[t] = excl;
    const int node = b * 256 + t;
    if (node < N_NODES) offs[node] = beg + excl;
    __syncthreads();

    for (int j = beg + t; j < end; j += 256) {
        const int2 v = bucketed[j];
        const int dl = (v.x >> 17) & 255;
        const int p  = beg + atomicAdd(&lcur[dl], 1);
        csr_ef[p] = make_int2(v.x & 0x1FFFF, v.y);
    }
}

// ===========================================================================
// Gather-aggregate over bf16 feature tables, fp32 accumulate.
// FEAT=128 writes PACKED bf16 output (feeds the MFMA GEMM).
// ===========================================================================
template <int FEAT>
__global__ __launch_bounds__(256) void aggregate(const void* __restrict__ featv,
                                                 const int* __restrict__ offs,
                                                 const int2* __restrict__ csr_ef,
                                                 const float* __restrict__ bias,
                                                 void* __restrict__ outv) {
    const int n    = (blockIdx.x * 256 + threadIdx.x) >> 6;
    const int lane = threadIdx.x & 63;
    if (n >= N_NODES) return;
    const int beg = offs[n], end = offs[n + 1];

    if constexpr (FEAT == 128) {
        const uint32* feat = (const uint32*)featv;
        float2 acc = make_float2(0.f, 0.f);
        int j = beg;
        for (; j + 3 < end; j += 4) {
            const int2 e0 = csr_ef[j],     e1 = csr_ef[j + 1];
            const int2 e2 = csr_ef[j + 2], e3 = csr_ef[j + 3];
            const uint32 v0 = feat[(size_t)e0.x * 64 + lane];
            const uint32 v1 = feat[(size_t)e1.x * 64 + lane];
            const uint32 v2 = feat[(size_t)e2.x * 64 + lane];
            const uint32 v3 = feat[(size_t)e3.x * 64 + lane];
            const float w0 = __int_as_float(e0.y), w1 = __int_as_float(e1.y);
            const float w2 = __int_as_float(e2.y), w3 = __int_as_float(e3.y);
            acc.x += w0 * bf16_lo(v0) + w1 * bf16_lo(v1) + w2 * bf16_lo(v2) + w3 * bf16_lo(v3);
            acc.y += w0 * bf16_hi(v0) + w1 * bf16_hi(v1) + w2 * bf16_hi(v2) + w3 * bf16_hi(v3);
        }
        for (; j < end; ++j) {
            const int2 e0 = csr_ef[j];
            const uint32 v = feat[(size_t)e0.x * 64 + lane];
            const float w = __int_as_float(e0.y);
            acc.x += w * bf16_lo(v);
            acc.y += w * bf16_hi(v);
        }
        ((uint32*)outv)[(size_t)n * 64 + lane] = pack_bf16x2(acc.x, acc.y);
    } else {
        const unsigned short* feat = (const unsigned short*)featv;
        float acc = bias[lane];
        int j = beg;
        for (; j + 3 < end; j += 4) {
            const int2 e0 = csr_ef[j],     e1 = csr_ef[j + 1];
            const int2 e2 = csr_ef[j + 2], e3 = csr_ef[j + 3];
            const float f0 = __uint_as_float((uint32)feat[(size_t)e0.x * 64 + lane] << 16);
            const float f1 = __uint_as_float((uint32)feat[(size_t)e1.x * 64 + lane] << 16);
            const float f2 = __uint_as_float((uint32)feat[(size_t)e2.x * 64 + lane] << 16);
            const float f3 = __uint_as_float((uint32)feat[(size_t)e3.x * 64 + lane] << 16);
            acc += __int_as_float(e0.y) * f0 + __int_as_float(e1.y) * f1
                 + __int_as_float(e2.y) * f2 + __int_as_float(e3.y) * f3;
        }
        for (; j < end; ++j) {
            const int2 e0 = csr_ef[j];
            acc += __int_as_float(e0.y)
                 * __uint_as_float((uint32)feat[(size_t)e0.x * 64 + lane] << 16);
        }
        ((float*)outv)[(size_t)n * 64 + lane] = acc;
    }
}

// ===========================================================================
// MFMA fused double GEMM: sup2b[N,64](bf16) = relu(aggPb@W1 + b1) @ W2.
// 512 threads = 8 waves; 128-row tile; mfma_f32_16x16x32_bf16.
// STATIC tile distribution (tile = blockIdx.x + k*gridDim.x) — no cross-block
// atomics, no LDS broadcast; every tile covered by construction every launch.
// ===========================================================================
__global__ __launch_bounds__(512) void gemm_fused(const uint32* __restrict__ aggPb,
                                                  const uint32* __restrict__ w1tb,
                                                  const float* __restrict__ b1,
                                                  const uint32* __restrict__ w2tb,
                                                  uint32* __restrict__ sup2b, int N) {
    __shared__ __align__(16) short As[128 * LDA];   // A tile / C bounce
    __shared__ __align__(16) short W1s[128 * LDA];  // W1T [n][k]
    __shared__ __align__(16) short W2s[64 * LDA];   // W2T [n][k]
    __shared__ __align__(16) short Ts[128 * LDA];   // relu intermediate [row][col]

    const int tid = threadIdx.x;

    // Stage W1T/W2T (once per block), coalesced uint4 (8 bf16 each)
    for (int i = tid; i < 128 * 16; i += 512)
        *(uint4*)&W1s[(i >> 4) * LDA + (i & 15) * 8] = ((const uint4*)w1tb)[i];
    for (int i = tid; i < 64 * 16; i += 512)
        *(uint4*)&W2s[(i >> 4) * LDA + (i & 15) * 8] = ((const uint4*)w2tb)[i];

    const int wave = tid >> 6;
    const int lane = tid & 63;
    const int m    = lane & 15;
    const int quad = lane >> 4;
    const int rowbase = (wave & 3) * 32;   // phase A rows (2 substrips of 16)
    const int colbase = (wave >> 2) * 64;  // phase A cols (4 tiles of 16)

    float b1r[4];
#pragma unroll
    for (int ct = 0; ct < 4; ++ct) b1r[ct] = b1[colbase + ct * 16 + m];

    for (int tile = blockIdx.x; tile < NTILES; tile += gridDim.x) {
        const int row0 = tile * 128;
        __syncthreads();   // prev iter's store reads of As done; W staging on first

        // ---- Stage A tile: 128 rows x 16 uint4, padded rows ----------------
#pragma unroll
        for (int i = 0; i < 4; ++i) {
            const int idx = i * 512 + tid;
            const int row = idx >> 4, c4 = idx & 15;
            const int grow = row0 + row;
            uint4 v = make_uint4(0u, 0u, 0u, 0u);
            if (grow < N) v = ((const uint4*)aggPb)[(size_t)grow * 16 + c4];
            *(uint4*)&As[row * LDA + c4 * 8] = v;
        }
        __syncthreads();

        // ---- Phase A: T = relu(A@W1 + b1) ----------------------------------
        bf16x8 afrag[2][4];
#pragma unroll
        for (int ss = 0; ss < 2; ++ss)
#pragma unroll
            for (int ch = 0; ch < 4; ++ch)
                afrag[ss][ch] = *(const bf16x8*)&As[(rowbase + ss * 16 + m) * LDA + ch * 32 + quad * 8];

        f32x4 acc[2][4];
#pragma unroll
        for (int ss = 0; ss < 2; ++ss)
#pragma unroll
            for (int ct = 0; ct < 4; ++ct) acc[ss][ct] = (f32x4){0.f, 0.f, 0.f, 0.f};

#pragma unroll
        for (int ct = 0; ct < 4; ++ct) {
            bf16x8 bfr[4];
#pragma unroll
            for (int ch = 0; ch < 4; ++ch)
                bfr[ch] = *(const bf16x8*)&W1s[(colbase + ct * 16 + m) * LDA + ch * 32 + quad * 8];
#pragma unroll
            for (int ss = 0; ss < 2; ++ss)
#pragma unroll
                for (int ch = 0; ch < 4; ++ch)
                    acc[ss][ct] = __builtin_amdgcn_mfma_f32_16x16x32_bf16(
                        afrag[ss][ch], bfr[ch], acc[ss][ct], 0, 0, 0);
        }

        // bias + relu -> Ts[row][col] bf16
#pragma unroll
        for (int ss = 0; ss < 2; ++ss)
#pragma unroll
            for (int ct = 0; ct < 4; ++ct)
#pragma unroll
                for (int r = 0; r < 4; ++r) {
                    const float v = fmaxf(acc[ss][ct][r] + b1r[ct], 0.f);
                    const int row = rowbase + ss * 16 + quad * 4 + r;
                    const int col = colbase + ct * 16 + m;
                    Ts[row * LDA + col] = (short)bf16_rne(v);
                }
        __syncthreads();   // T complete; also all As reads done

        // ---- Phase B: C = T @ W2 (each wave: 16 rows x 64 cols) ------------
        const int rb2 = wave * 16;
        bf16x8 tfrag[4];
#pragma unroll
        for (int ch = 0; ch < 4; ++ch)
            tfrag[ch] = *(const bf16x8*)&Ts[(rb2 + m) * LDA + ch * 32 + quad * 8];

        f32x4 acc2[4];
#pragma unroll
        for (int ct = 0; ct < 4; ++ct) acc2[ct] = (f32x4){0.f, 0.f, 0.f, 0.f};
#pragma unroll
        for (int ct = 0; ct < 4; ++ct)
#pragma unroll
            for (int ch = 0; ch < 4; ++ch) {
                const bf16x8 bfr = *(const bf16x8*)&W2s[(ct * 16 + m) * LDA + ch * 32 + quad * 8];
                acc2[ct] = __builtin_amdgcn_mfma_f32_16x16x32_bf16(
                    tfrag[ch], bfr, acc2[ct], 0, 0, 0);
            }

        // ---- C bounce via As (bf16), then coalesced store ------------------
#pragma unroll
        for (int ct = 0; ct < 4; ++ct)
#pragma unroll
            for (int r = 0; r < 4; ++r) {
                const int row = rb2 + quad * 4 + r;
                const int col = ct * 16 + m;
                As[row * LDA + col] = (short)bf16_rne(acc2[ct][r]);
            }
        __syncthreads();
#pragma unroll
        for (int i = 0; i < 2; ++i) {
            const int idx = i * 512 + tid;      // 128 rows x 8 uint4 (64 bf16)
            const int row = idx >> 3, c4 = idx & 7;
            if (row0 + row < N)
                ((uint4*)sup2b)[(size_t)(row0 + row) * 8 + c4] = *(uint4*)&As[row * LDA + c4 * 8];
        }
    }
}

extern "C" void kernel_launch(void* const* d_in, const int* in_sizes, int n_in,
                              void* d_out, int out_size, void* d_ws, size_t ws_size,
                              hipStream_t stream) {
    const float* x  = (const float*)d_in[0];
    const int*   ei = (const int*)d_in[1];   // [2, E]: row 0 = dst, row 1 = src
    const float* ew = (const float*)d_in[2];
    const float* W1 = (const float*)d_in[3];
    const float* b1 = (const float*)d_in[4];
    const float* W2 = (const float*)d_in[5];
    const float* b2 = (const float*)d_in[6];
    float* out = (float*)d_out;

    const int* dstIdx = ei;
    const int* srcIdx = ei + N_EDGES;

    // Workspace (~90 MB):
    //   xb [N*64 uint, 25.6 MB] -> aliased by sup2b
    //   aggPb bf16 [N*64 uint, 25.6 MB]; bucketed aliases it during CSR build
    //   w1tb/w2tb after aggPb; csr_ef [E int2, 12.8 MB]; padded counters after.
    uint32* xb      = (uint32*)d_ws;
    uint32* aggPb   = xb + (size_t)N_NODES * 64;
    uint32* w1tb    = aggPb + (size_t)N_NODES * 64;   // 8192 uint
    uint32* w2tb    = w1tb + 128 * 64;                // 4096 uint
    int2*   csr_ef  = (int2*)(xb + (size_t)N_NODES * 64 + (size_t)N_NODES * 128);
    int*    bktCnt  = (int*)(csr_ef + N_EDGES);   // NB*PAD (padded)
    int*    bCur    = bktCnt + NB * PAD;          // NB*PAD (init by bucket_scan)
    int*    bBase   = bCur + NB * PAD;            // NB+1
    int*    offs    = bBase + NB + 1;             // N+1
    int2*   bucketed = (int2*)aggPb;              // alias (dead before aggPb written)
    uint32* sup2b   = xb;                         // alias (dead before sup2b written)

    // --- zero padded bucket counts ---
    (void)hipMemsetAsync(bktCnt, 0, (size_t)NB * PAD * sizeof(int), stream);
    conv_x<<<(N_NODES * 64 + 255) / 256, 256, 0, stream>>>(x, xb);
    conv_w<<<48, 256, 0, stream>>>(W1, W2, w1tb, w2tb);

    // --- bucketed CSR build ---
    bucket_hist<<<NB, 256, 0, stream>>>(dstIdx, bktCnt);
    bucket_scan<<<1, 512, 0, stream>>>(bktCnt, bBase, bCur, offs);
    bucket_scatter2<<<SC_BLOCKS, 256, 0, stream>>>(dstIdx, srcIdx, ew, bCur, bucketed);
    bucket_csr<<<NB, 256, 0, stream>>>(bucketed, bBase, offs, csr_ef);

    // --- Layer 1 aggregate-first: aggPb = bf16(A @ x) ---
    aggregate<128><<<(N_NODES * 64) / 256, 256, 0, stream>>>(xb, offs, csr_ef,
                                                             nullptr, aggPb);
    // --- Fused transform (MFMA): sup2b = bf16(relu(aggPb@W1 + b1) @ W2) ---
    gemm_fused<<<256, 512, 0, stream>>>(aggPb, w1tb, b1, w2tb, sup2b, N_NODES);

    // --- Layer 2 aggregate (bf16 gather), bias b2 folded in ---
    aggregate<64><<<(N_NODES * 64) / 256, 256, 0, stream>>>(sup2b, offs, csr_ef,
                                                            b2, out);
}